// Round 3
// baseline (246.688 us; speedup 1.0000x reference)
//
#include <hip/hip_runtime.h>

// Problem constants
#define LDIM 16384
#define KDIM 288
#define ODIM 64
#define BDIM 8

typedef float f32x4 __attribute__((ext_vector_type(4)));

// ---------------------------------------------------------------------------
// fp32, occupancy-fixed version.
//
// Round-2 diagnosis: VALU busy 45us + LDS pipe busy 46us = 90us measured --
// ZERO overlap between the two pipes. 80KB LDS -> 2 blocks/CU -> 2 waves/SIMD
// moving in barrier lockstep: when a wave is in its ds_read cluster, the one
// other wave on the SIMD is too. Fix: k-chunk 32 -> 16 halves LDS to 40KB ->
// 4 blocks/CU = 4 waves/SIMD, independent per-block barriers anti-phase the
// blocks, VALU and LDS pipes overlap.
//
//   * 8l x 8o per-thread microtile (64 acc regs), 1.0 FMA/LDS-byte
//   * global_load_lds staging (wave-linear rows), double-buffered, one
//     barrier per k-chunk, prefetch distance 2
//   * block 256 threads = 256 l x 64 o; grid 512; k-chunk 16 (18 chunks)
//   * LDS 2x16KB (x) + 2x4KB (w) = 40 KB -> 4 blocks/CU
// ---------------------------------------------------------------------------
__global__ __launch_bounds__(256, 4) void gauss_fp32(
    const float* __restrict__ x, const float* __restrict__ w,
    const float* __restrict__ bias, const float* __restrict__ gammap,
    float* __restrict__ out) {
  // [2][16][256] x-chunks, then [2][16][64] w-chunks. 40 KB total.
  __shared__ float lds[2 * 4096 + 2 * 1024];
  float* const xs0 = lds;
  float* const ws0 = lds + 8192;
  float* const red = ws0 + 1024;  // aliases w buffer 1 (barrier-sequenced)

  const int t = threadIdx.x;
  const int lane = t & 63;
  const int wvid = t >> 6;
  const int tl = t >> 3;  // 0..31 : l-block = tl*8
  const int to = t & 7;   // 0..7  : o-block = to*8

  const long g0 = (long)blockIdx.x * 256;  // global row (b*L + l); 256 | 16384
  const int bidx = (int)(g0 >> 14);
  const int l0 = (int)(g0 & (LDIM - 1));
  const float* xb = x + (long)bidx * ((long)KDIM * LDIM) + l0;

  // One global_load_lds instr stages one 1 KB row (wave-uniform LDS base,
  // per-lane global addr = row base + lane*16B).
#define STAGE(KC, BUF)                                                         \
  {                                                                            \
    const float* xsrc = xb + (long)((KC) * 16) * LDIM + lane * 4;              \
    float* xdst = xs0 + (BUF) * 4096;                                          \
    _Pragma("unroll") for (int i = 0; i < 4; ++i) {                            \
      int r = wvid * 4 + i;                                                    \
      __builtin_amdgcn_global_load_lds(                                        \
          (const __attribute__((address_space(1))) unsigned int*)(void*)       \
              (xsrc + (long)r * LDIM),                                         \
          (__attribute__((address_space(3))) unsigned int*)(void*)             \
              (xdst + r * 256),                                                \
          16, 0, 0);                                                           \
    }                                                                          \
    __builtin_amdgcn_global_load_lds(                                          \
        (const __attribute__((address_space(1))) unsigned int*)(void*)         \
            (w + (KC) * 1024 + wvid * 256 + lane * 4),                         \
        (__attribute__((address_space(3))) unsigned int*)(void*)               \
            (ws0 + (BUF) * 1024 + wvid * 256),                                 \
        16, 0, 0);                                                             \
  }

  // ---- issue chunk-0 staging first; cw partial sums hide under it
  STAGE(0, 0)
  const float gamma = gammap[0];
  {
    const int seg = t >> 6, o = t & 63;
    float s = 0.f;
#pragma unroll 8
    for (int k = seg * 72; k < seg * 72 + 72; ++k) {
      float v = w[k * 64 + o];  // lanes cover o=0..63 -> coalesced 256 B
      s = fmaf(v, v, s);
    }
    red[t] = s;
  }
  __syncthreads();  // red visible; implicit vmcnt(0) also drains STAGE(0)

  float cwv[8], bv[8];
#pragma unroll
  for (int j = 0; j < 8; ++j) {
    int o = to * 8 + j;
    cwv[j] = -gamma * (red[o] + red[o + 64] + red[o + 128] + red[o + 192]);
    bv[j] = bias[o];
  }
  __syncthreads();  // all red reads done before STAGE(1) overwrites it
  STAGE(1, 1)

  float acc[8][8];
#pragma unroll
  for (int i = 0; i < 8; ++i)
#pragma unroll
    for (int j = 0; j < 8; ++j) acc[i][j] = 0.f;
  float x2a[8] = {0.f, 0.f, 0.f, 0.f, 0.f, 0.f, 0.f, 0.f};

  // Main loop: iteration kc computes from buf (kc&1), staged by STAGE(kc),
  // drained by the barrier at the end of iteration kc-1 (or pre-loop).
#pragma unroll 1
  for (int kc = 0; kc < 18; ++kc) {
    const float* xp = xs0 + (kc & 1) * 4096;
    const float* wp = ws0 + (kc & 1) * 1024;
#pragma unroll 4
    for (int k = 0; k < 16; ++k) {
      f32x4 xa0 = *(const f32x4*)(xp + k * 256 + tl * 8);
      f32x4 xa1 = *(const f32x4*)(xp + k * 256 + tl * 8 + 4);
      f32x4 wa0 = *(const f32x4*)(wp + k * 64 + to * 8);
      f32x4 wa1 = *(const f32x4*)(wp + k * 64 + to * 8 + 4);
      float xv[8];
#pragma unroll
      for (int i = 0; i < 4; ++i) { xv[i] = xa0[i]; xv[i + 4] = xa1[i]; }
#pragma unroll
      for (int i = 0; i < 8; ++i) x2a[i] = fmaf(xv[i], xv[i], x2a[i]);
#pragma unroll
      for (int i = 0; i < 8; ++i) {
#pragma unroll
        for (int j = 0; j < 4; ++j) {
          acc[i][j] = fmaf(xv[i], wa0[j], acc[i][j]);
          acc[i][j + 4] = fmaf(xv[i], wa1[j], acc[i][j + 4]);
        }
      }
    }
    __syncthreads();  // reads of buf(kc&1) done; drains STAGE(kc+1)
    if (kc < 16) STAGE(kc + 2, kc & 1)
  }

  // ---- epilogue: e = -gamma*(x2 + w2 - 2*xw); out = exp(e) + bias
  const float coef = 2.f * gamma;
  float* outw = out + (g0 + (long)tl * 8) * 64 + to * 8;
#pragma unroll
  for (int i = 0; i < 8; ++i) {
    const float cx = -gamma * x2a[i];
    f32x4 r0, r1;
#pragma unroll
    for (int j = 0; j < 4; ++j) {
      r0[j] = __expf(fmaf(coef, acc[i][j], cx + cwv[j])) + bv[j];
      r1[j] = __expf(fmaf(coef, acc[i][j + 4], cx + cwv[j + 4])) + bv[j + 4];
    }
    *(f32x4*)(outw + i * 64) = r0;
    *(f32x4*)(outw + i * 64 + 4) = r1;
  }
#undef STAGE
}

extern "C" void kernel_launch(void* const* d_in, const int* in_sizes, int n_in,
                              void* d_out, int out_size, void* d_ws, size_t ws_size,
                              hipStream_t stream) {
  const float* x = (const float*)d_in[0];      // [8, 288, 16384]
  const float* w = (const float*)d_in[1];      // [64, 32, 3, 3] -> flat 18432
  const float* b = (const float*)d_in[2];      // [64]
  const float* gamma = (const float*)d_in[3];  // scalar
  float* out = (float*)d_out;                  // [8, 16384, 64]

  (void)d_ws; (void)ws_size;
  gauss_fp32<<<512, 256, 0, stream>>>(x, w, b, gamma, out);
}

// Round 4
// 232.626 us; speedup vs baseline: 1.0605x; 1.0605x over previous
//
#include <hip/hip_runtime.h>

// Problem constants
#define LDIM 16384
#define KDIM 288
#define ODIM 64
#define BDIM 8

typedef float f32x4 __attribute__((ext_vector_type(4)));
typedef short bf16x8 __attribute__((ext_vector_type(8)));  // 8 bf16 in 4 VGPRs

// fp32 -> bf16 round-to-nearest-even
__device__ __forceinline__ short f2bf(float f) {
  unsigned u = __builtin_bit_cast(unsigned, f);
  unsigned r = u + 0x7FFFu + ((u >> 16) & 1u);
  return (short)(r >> 16);
}

// ---------------------------------------------------------------------------
// Pre-kernel, grid=10: blocks 0..8 swizzle W k-chunk kc=blockIdx into MFMA
// B-fragment order (bf16); block 9 computes cw[o] = -gamma * sum_k w[k][o]^2.
// wv[k][o] = w_flat[k*64 + o]  (memory reinterpretation per reference)
// ---------------------------------------------------------------------------
__global__ __launch_bounds__(256) void gauss_pre(const float* __restrict__ w,
                                                 const float* __restrict__ gammap,
                                                 short* __restrict__ wfrag,
                                                 float* __restrict__ cw) {
  int tid = threadIdx.x;
  int blk = blockIdx.x;

  if (blk < 9) {
    int kc = blk;
    int ln = tid & 63;
    int nt = tid >> 6;
    int k0 = kc * 32 + (ln >> 4) * 8;
    int n = nt * 16 + (ln & 15);
    bf16x8 v;
#pragma unroll
    for (int j = 0; j < 8; ++j) v[j] = f2bf(w[(k0 + j) * 64 + n]);
    *(bf16x8*)(wfrag + ((kc * 4 + nt) * 64 + ln) * 8) = v;
  } else {
    __shared__ float red[256];
    int o = tid & 63;
    int seg = tid >> 6;
    float s = 0.f;
#pragma unroll 8
    for (int k = seg * 72; k < seg * 72 + 72; ++k) {
      float v = w[k * 64 + o];
      s = fmaf(v, v, s);
    }
    red[tid] = s;
    __syncthreads();
    if (tid < 64) {
      float t = red[tid] + red[tid + 64] + red[tid + 128] + red[tid + 192];
      cw[tid] = -gammap[0] * t;
    }
  }
}

// ---------------------------------------------------------------------------
// Main kernel: NO-LDS streaming MFMA.
//
// Round-3 diagnosis: fp32-VALU structure is pinned at ~sum(LDS 46us, VALU
// 45us) because per-thread-output=64 forces 2 waves/SIMD and barrier-locked
// phases. This version moves the 64-FMA/element onto the idle matrix pipe
// and deletes LDS entirely:
//   * A-fragment (x) loaded straight from global: lane (g=lane>>4, m=lane&15)
//     needs x[k=kc*32+g*8+j][l=base+m] -> 8 global_load_dword, each instr =
//     4x64B segments; the two t-tiles pair into full 128B lines. Each x
//     element is read exactly once chip-wide (block owns 128 l x all 64 o).
//   * x^2 accumulated in fp32 from the loaded values BEFORE bf16 conversion
//     (only the cross-term xw is bf16: expected extra absmax ~3e-4).
//   * B-fragments (w, 36KB bf16 pre-swizzled) read from global per kc —
//     L2/L3-hot, shared by all blocks.
//   * zero __syncthreads, zero LDS, register prefetch distance 1;
//     grid 1024 x 256 thr -> 4 blocks/CU, 4 waves/SIMD, ~110 VGPR.
// Pipe budget: HBM 30us (binding), VALU ~6us, MFMA ~2.4us, LDS 0.
// ---------------------------------------------------------------------------
__global__ __launch_bounds__(256, 4) void gauss_main(
    const float* __restrict__ x, const short* __restrict__ wfrag,
    const float* __restrict__ cw, const float* __restrict__ bias,
    const float* __restrict__ gammap, float* __restrict__ out) {
  const int t = threadIdx.x;
  const int lane = t & 63;
  const int wvid = t >> 6;
  const int m = lane & 15;   // n-col within 16 (o) / l-col for A
  const int g = lane >> 4;   // k-group (0..3)

  const long g0 = (long)blockIdx.x * 128;  // global row (b*L + l); 128 | 16384
  const int bidx = (int)(g0 >> 14);
  const int l0 = (int)(g0 & (LDIM - 1));

  // lane's x column pointer (t-tile 0); t-tile 1 is +16 floats
  const float* xc = x + (long)bidx * ((long)KDIM * LDIM) +
                    (long)(g * 8) * LDIM + (l0 + wvid * 32 + m);

  float xv0[8], xv1[8], nx0[8], nx1[8];
#pragma unroll
  for (int j = 0; j < 8; ++j) {
    xv0[j] = xc[(long)j * LDIM];
    xv1[j] = xc[(long)j * LDIM + 16];
  }

  const f32x4 zero = {0.f, 0.f, 0.f, 0.f};
  f32x4 acc[2][4];
#pragma unroll
  for (int tt = 0; tt < 2; ++tt)
#pragma unroll
    for (int nt = 0; nt < 4; ++nt) acc[tt][nt] = zero;
  float x2a[2] = {0.f, 0.f};

#pragma unroll 1
  for (int kc = 0; kc < 9; ++kc) {
    // prefetch next k-chunk's x (independent of this chunk's compute)
    if (kc < 8) {
      const float* nxp = xc + (long)((kc + 1) * 32) * LDIM;
#pragma unroll
      for (int j = 0; j < 8; ++j) {
        nx0[j] = nxp[(long)j * LDIM];
        nx1[j] = nxp[(long)j * LDIM + 16];
      }
    }

    // B fragments for this kc (L2-hot, 4 x b128 per lane)
    const short* wp = wfrag + ((kc * 4) * 64 + lane) * 8;
    bf16x8 bfr[4];
#pragma unroll
    for (int nt = 0; nt < 4; ++nt) bfr[nt] = *(const bf16x8*)(wp + nt * 512);

    // convert + x^2 (fp32, pre-conversion values)
    bf16x8 a0, a1;
#pragma unroll
    for (int j = 0; j < 8; ++j) {
      x2a[0] = fmaf(xv0[j], xv0[j], x2a[0]);
      a0[j] = f2bf(xv0[j]);
    }
#pragma unroll
    for (int j = 0; j < 8; ++j) {
      x2a[1] = fmaf(xv1[j], xv1[j], x2a[1]);
      a1[j] = f2bf(xv1[j]);
    }

#pragma unroll
    for (int nt = 0; nt < 4; ++nt) {
      acc[0][nt] = __builtin_amdgcn_mfma_f32_16x16x32_bf16(a0, bfr[nt], acc[0][nt], 0, 0, 0);
      acc[1][nt] = __builtin_amdgcn_mfma_f32_16x16x32_bf16(a1, bfr[nt], acc[1][nt], 0, 0, 0);
    }

    if (kc < 8) {
#pragma unroll
      for (int j = 0; j < 8; ++j) {
        xv0[j] = nx0[j];
        xv1[j] = nx1[j];
      }
    }
  }

  // ---- finish |x|^2 across the 4 k-groups
#pragma unroll
  for (int tt = 0; tt < 2; ++tt) {
    x2a[tt] += __shfl_xor(x2a[tt], 16, 64);
    x2a[tt] += __shfl_xor(x2a[tt], 32, 64);
  }

  const float gamma = gammap[0];
  const float coef = 2.f * gamma;
  float cwv[4], bv[4];
#pragma unroll
  for (int nt = 0; nt < 4; ++nt) {
    cwv[nt] = cw[nt * 16 + m];
    bv[nt] = bias[nt * 16 + m];
  }

  // ---- epilogue: C/D layout col=lane&15 (=o), row=(lane>>4)*4+r (=l)
  // store dword: 16 lanes consecutive o -> 4x64B segments per instr
  float* ob = out + (g0 + wvid * 32) * 64;
#pragma unroll
  for (int tt = 0; tt < 2; ++tt) {
#pragma unroll
    for (int r = 0; r < 4; ++r) {
      int row = g * 4 + r;  // 0..15 within the t-tile
      float x2v = __shfl(x2a[tt], (lane & 48) | row, 64);
      float cx = -gamma * x2v;
      int lrow = tt * 16 + row;  // 0..31 within wave tile
#pragma unroll
      for (int nt = 0; nt < 4; ++nt) {
        float e = fmaf(coef, acc[tt][nt][r], cx + cwv[nt]);  // -gamma*d2
        ob[lrow * 64 + nt * 16 + m] = __expf(e) + bv[nt];
      }
    }
  }
}

extern "C" void kernel_launch(void* const* d_in, const int* in_sizes, int n_in,
                              void* d_out, int out_size, void* d_ws, size_t ws_size,
                              hipStream_t stream) {
  const float* x = (const float*)d_in[0];      // [8, 288, 16384]
  const float* w = (const float*)d_in[1];      // [64, 32, 3, 3] -> flat 18432
  const float* b = (const float*)d_in[2];      // [64]
  const float* gamma = (const float*)d_in[3];  // scalar
  float* out = (float*)d_out;                  // [8, 16384, 64]

  short* wfrag = (short*)d_ws;                // 18432 bf16 = 36864 B
  float* cw = (float*)((char*)d_ws + 36864);  // 64 floats

  gauss_pre<<<10, 256, 0, stream>>>(w, gamma, wfrag, cw);
  gauss_main<<<1024, 256, 0, stream>>>(x, wfrag, cw, b, gamma, out);
}

// Round 5
// 231.263 us; speedup vs baseline: 1.0667x; 1.0059x over previous
//
#include <hip/hip_runtime.h>

// Problem constants
#define LDIM 16384
#define KDIM 288
#define ODIM 64
#define BDIM 8

typedef float f32x4 __attribute__((ext_vector_type(4)));
typedef short bf16x8 __attribute__((ext_vector_type(8)));  // 8 bf16 in 4 VGPRs

// fp32 -> bf16 round-to-nearest-even
__device__ __forceinline__ short f2bf(float f) {
  unsigned u = __builtin_bit_cast(unsigned, f);
  unsigned r = u + 0x7FFFu + ((u >> 16) & 1u);
  return (short)(r >> 16);
}

// ---------------------------------------------------------------------------
// Pre-kernel, grid=10: blocks 0..8 swizzle W k-chunk kc=blockIdx into MFMA
// B-fragment order (bf16); block 9 computes cw[o] = -gamma * sum_k w[k][o]^2.
// wv[k][o] = w_flat[k*64 + o]  (memory reinterpretation per reference)
// ---------------------------------------------------------------------------
__global__ __launch_bounds__(256) void gauss_pre(const float* __restrict__ w,
                                                 const float* __restrict__ gammap,
                                                 short* __restrict__ wfrag,
                                                 float* __restrict__ cw) {
  int tid = threadIdx.x;
  int blk = blockIdx.x;

  if (blk < 9) {
    int kc = blk;
    int ln = tid & 63;
    int nt = tid >> 6;
    int k0 = kc * 32 + (ln >> 4) * 8;
    int n = nt * 16 + (ln & 15);
    bf16x8 v;
#pragma unroll
    for (int j = 0; j < 8; ++j) v[j] = f2bf(w[(k0 + j) * 64 + n]);
    *(bf16x8*)(wfrag + ((kc * 4 + nt) * 64 + ln) * 8) = v;
  } else {
    __shared__ float red[256];
    int o = tid & 63;
    int seg = tid >> 6;
    float s = 0.f;
#pragma unroll 8
    for (int k = seg * 72; k < seg * 72 + 72; ++k) {
      float v = w[k * 64 + o];
      s = fmaf(v, v, s);
    }
    red[tid] = s;
    __syncthreads();
    if (tid < 64) {
      float t = red[tid] + red[tid + 64] + red[tid + 128] + red[tid + 192];
      cw[tid] = -gammap[0] * t;
    }
  }
}

// ---------------------------------------------------------------------------
// Main kernel: streaming MFMA, w resident in LDS.
//
// Round-4 diagnosis: per-chunk w-fragment GLOBAL loads were issued after the
// x prefetch; vmcnt is FIFO, so consuming w for the MFMAs forced vmcnt(0),
// draining the prefetch too -> chunk-serialized HBM stalls -> 2.6 TB/s.
// Fix: wfrag (36 KB) staged to LDS ONCE at entry (9 linear global_load_lds
// per wave + one barrier); per-chunk B-fragments come via ds_read_b128
// (lgkmcnt, independent counter). The loop's only vmem is the 16-dword x
// prefetch, so the compiler's counted vmcnt(16) keeps it in flight across
// the entire next chunk (~6400 cy at BW-bound >> ~1500 cy loaded latency).
//   * x^2 in fp32 pre-conversion; only cross-term xw is bf16 (absmax ~0.016)
//   * zero barriers in the loop (LDS read-only after staging)
//   * grid 1024 x 256 thr, LDS 36 KB -> 4 blocks/CU, VGPR ~120
// Pipe budget: HBM 185 MB ~ 30 us (binding), VALU ~6 us, MFMA ~2.4 us.
// ---------------------------------------------------------------------------
__global__ __launch_bounds__(256, 4) void gauss_main(
    const float* __restrict__ x, const short* __restrict__ wfrag,
    const float* __restrict__ cw, const float* __restrict__ bias,
    const float* __restrict__ gammap, float* __restrict__ out) {
  __shared__ short wlds[18432];  // 36 KB, fragment order (identical to wfrag)

  const int t = threadIdx.x;
  const int lane = t & 63;
  const int wvid = t >> 6;
  const int m = lane & 15;   // o-col within 16 / l-col for A
  const int g = lane >> 4;   // k-group (0..3)

  // ---- stage wfrag -> LDS, linear 1 KB rows (wave w: rows w*9 .. w*9+8)
#pragma unroll
  for (int i = 0; i < 9; ++i) {
    int blk = wvid * 9 + i;
    __builtin_amdgcn_global_load_lds(
        (const __attribute__((address_space(1))) unsigned int*)(void*)
            ((const char*)wfrag + blk * 1024 + lane * 16),
        (__attribute__((address_space(3))) unsigned int*)(void*)
            ((char*)wlds + blk * 1024),
        16, 0, 0);
  }

  const long g0 = (long)blockIdx.x * 128;  // global row (b*L + l); 128 | 16384
  const int bidx = (int)(g0 >> 14);
  const int l0 = (int)(g0 & (LDIM - 1));

  // lane's x column pointer (t-tile 0); t-tile 1 is +16 floats
  const float* xc = x + (long)bidx * ((long)KDIM * LDIM) +
                    (long)(g * 8) * LDIM + (l0 + wvid * 32 + m);

  // chunk-0 x loads overlap the LDS staging
  float xv0[8], xv1[8], nx0[8], nx1[8];
#pragma unroll
  for (int j = 0; j < 8; ++j) {
    xv0[j] = xc[(long)j * LDIM];
    xv1[j] = xc[(long)j * LDIM + 16];
  }

  __syncthreads();  // wlds ready (implicit vmcnt(0)+lgkmcnt(0) drain)

  const f32x4 zero = {0.f, 0.f, 0.f, 0.f};
  f32x4 acc[2][4];
#pragma unroll
  for (int tt = 0; tt < 2; ++tt)
#pragma unroll
    for (int nt = 0; nt < 4; ++nt) acc[tt][nt] = zero;
  float x2a[2] = {0.f, 0.f};

#pragma unroll 1
  for (int kc = 0; kc < 9; ++kc) {
    // prefetch next k-chunk's x — the ONLY vmem in the loop body
    if (kc < 8) {
      const float* nxp = xc + (long)((kc + 1) * 32) * LDIM;
#pragma unroll
      for (int j = 0; j < 8; ++j) {
        nx0[j] = nxp[(long)j * LDIM];
        nx1[j] = nxp[(long)j * LDIM + 16];
      }
    }

    // B fragments from LDS (4 x ds_read_b128, contiguous -> conflict-free)
    const short* wp = wlds + ((kc * 4) * 64 + lane) * 8;
    bf16x8 bfr[4];
#pragma unroll
    for (int nt = 0; nt < 4; ++nt) bfr[nt] = *(const bf16x8*)(wp + nt * 512);

    // convert + x^2 (fp32, pre-conversion values)
    bf16x8 a0, a1;
#pragma unroll
    for (int j = 0; j < 8; ++j) {
      x2a[0] = fmaf(xv0[j], xv0[j], x2a[0]);
      a0[j] = f2bf(xv0[j]);
    }
#pragma unroll
    for (int j = 0; j < 8; ++j) {
      x2a[1] = fmaf(xv1[j], xv1[j], x2a[1]);
      a1[j] = f2bf(xv1[j]);
    }

#pragma unroll
    for (int nt = 0; nt < 4; ++nt) {
      acc[0][nt] = __builtin_amdgcn_mfma_f32_16x16x32_bf16(a0, bfr[nt], acc[0][nt], 0, 0, 0);
      acc[1][nt] = __builtin_amdgcn_mfma_f32_16x16x32_bf16(a1, bfr[nt], acc[1][nt], 0, 0, 0);
    }

    if (kc < 8) {
#pragma unroll
      for (int j = 0; j < 8; ++j) {
        xv0[j] = nx0[j];
        xv1[j] = nx1[j];
      }
    }
  }

  // ---- finish |x|^2 across the 4 k-groups
#pragma unroll
  for (int tt = 0; tt < 2; ++tt) {
    x2a[tt] += __shfl_xor(x2a[tt], 16, 64);
    x2a[tt] += __shfl_xor(x2a[tt], 32, 64);
  }

  const float gamma = gammap[0];
  const float coef = 2.f * gamma;
  float cwv[4], bv[4];
#pragma unroll
  for (int nt = 0; nt < 4; ++nt) {
    cwv[nt] = cw[nt * 16 + m];
    bv[nt] = bias[nt * 16 + m];
  }

  // ---- epilogue: C/D layout col=lane&15 (=o), row=(lane>>4)*4+r (=l)
  float* ob = out + (g0 + wvid * 32) * 64;
#pragma unroll
  for (int tt = 0; tt < 2; ++tt) {
#pragma unroll
    for (int r = 0; r < 4; ++r) {
      int row = g * 4 + r;  // 0..15 within the t-tile
      float x2v = __shfl(x2a[tt], (lane & 48) | row, 64);
      float cx = -gamma * x2v;
      int lrow = tt * 16 + row;  // 0..31 within wave tile
#pragma unroll
      for (int nt = 0; nt < 4; ++nt) {
        float e = fmaf(coef, acc[tt][nt][r], cx + cwv[nt]);  // -gamma*d2
        ob[lrow * 64 + nt * 16 + m] = __expf(e) + bv[nt];
      }
    }
  }
}

extern "C" void kernel_launch(void* const* d_in, const int* in_sizes, int n_in,
                              void* d_out, int out_size, void* d_ws, size_t ws_size,
                              hipStream_t stream) {
  const float* x = (const float*)d_in[0];      // [8, 288, 16384]
  const float* w = (const float*)d_in[1];      // [64, 32, 3, 3] -> flat 18432
  const float* b = (const float*)d_in[2];      // [64]
  const float* gamma = (const float*)d_in[3];  // scalar
  float* out = (float*)d_out;                  // [8, 16384, 64]

  short* wfrag = (short*)d_ws;                // 18432 bf16 = 36864 B
  float* cw = (float*)((char*)d_ws + 36864);  // 64 floats

  gauss_pre<<<10, 256, 0, stream>>>(w, gamma, wfrag, cw);
  gauss_main<<<1024, 256, 0, stream>>>(x, wfrag, cw, b, gamma, out);
}

// Round 6
// 228.513 us; speedup vs baseline: 1.0795x; 1.0120x over previous
//
#include <hip/hip_runtime.h>

// Problem constants
#define LDIM 16384
#define KDIM 288
#define ODIM 64
#define BDIM 8

typedef float f32x4 __attribute__((ext_vector_type(4)));
typedef short bf16x8 __attribute__((ext_vector_type(8)));  // 8 bf16 in 4 VGPRs

// fp32 -> bf16 round-to-nearest-even
__device__ __forceinline__ short f2bf(float f) {
  unsigned u = __builtin_bit_cast(unsigned, f);
  unsigned r = u + 0x7FFFu + ((u >> 16) & 1u);
  return (short)(r >> 16);
}

// ---------------------------------------------------------------------------
// Single-kernel MFMA version with a counted-vmcnt (T3/T4) pipeline.
//
// Diagnosis history: R0 (gload_lds staging + __syncthreads) and R4/R5
// (register-prefetch streaming) ALL land ~70us (~2.5 TB/s) vs the 30us HBM
// floor. Shared defects they had, all removed here:
//   * __syncthreads drains vmcnt(0) -> stage issued 1 compute-phase earlier
//     gets serialized into every chunk (m97 barrier-drain). Now: raw
//     s_barrier + s_waitcnt vmcnt(4) -- stage(kc+1) stays in flight across
//     the barrier; we only ever wait on the stage issued TWO barriers ago.
//   * separate pre-kernel launch: merged (w fragments + cw built in-kernel).
//   * R0's 4-way-bank A-reads: staging SOURCE is swizzled at 16B granularity
//     (piece p of row k holds l4 = (p - 2*(k>>3)) & 31) so linear-LDS
//     ds_read_b32 A-fragments hit each bank exactly 2x (free, m136).
// Geometry: block 256 thr = 128 l x 64 o, grid 1024; chunk K=32;
// LDS = 2x16KB x-dbuf + 36KB w-frags + 1KB scratch = 69.6KB -> 2 blocks/CU.
// In-flight HBM per CU >= 32KB >> 9KB Little's-law min for 6.3 TB/s.
// Pipe budget: HBM ~30us (binding); LDS/VALU/MFMA all hide under it.
// ---------------------------------------------------------------------------
__global__ __launch_bounds__(256, 2) void gauss_all(
    const float* __restrict__ x, const float* __restrict__ w,
    const float* __restrict__ bias, const float* __restrict__ gammap,
    float* __restrict__ out) {
  __shared__ float xs[2][4096];   // 2 x 16 KB x chunks (swizzled pieces)
  __shared__ short wlds[36 * 512];  // 36 KB bf16 w fragments (36 rows)
  __shared__ float red[256];        // cw reduction scratch

  const int t = threadIdx.x;
  const int lane = t & 63;
  const int wvid = t >> 6;
  const int m = lane & 15;  // o-col of C / l-row of A
  const int g = lane >> 4;  // k-group (0..3)

  const long g0 = (long)blockIdx.x * 128;  // global row (b*L + l); 128|16384
  const int bidx = (int)(g0 >> 14);
  const int l0 = (int)(g0 & (LDIM - 1));
  const float* xb = x + (long)bidx * ((long)KDIM * LDIM) + l0;

  // Swizzled-source staging: chunk = 32 k-rows x 32 pieces (16B each).
  // Piece slot (k, p) holds x[k][4*l4..+4) with l4 = (p - 2*(k>>3)) & 31.
  // Instr s covers slots s*64+lane -> k = s*2+(lane>>5), p = lane&31.
  const float* sp[4];
#pragma unroll
  for (int i = 0; i < 4; ++i) {
    int s = wvid * 4 + i;
    int k = s * 2 + (lane >> 5);
    int l4s = ((lane & 31) - 2 * (k >> 3)) & 31;
    sp[i] = xb + (long)k * LDIM + l4s * 4;
  }

#define STAGE(KC, BUF)                                                        \
  {                                                                           \
    _Pragma("unroll") for (int i = 0; i < 4; ++i) {                           \
      __builtin_amdgcn_global_load_lds(                                       \
          (const __attribute__((address_space(1))) unsigned int*)(void*)      \
              (sp[i] + (long)(KC) * 32 * LDIM),                               \
          (__attribute__((address_space(3))) unsigned int*)(void*)            \
              (&xs[BUF][(wvid * 4 + i) * 256]),                               \
          16, 0, 0);                                                          \
    }                                                                         \
  }

  // ---- prologue: start DMA for chunks 0,1 immediately
  STAGE(0, 0)
  STAGE(1, 1)

  // w -> bf16 MFMA B-fragments in LDS (layout identical to R4/R5's proven
  // wfrag: row rr = kc*4+nt, lane holds 8 k-consecutive bf16 for col n)
#pragma unroll
  for (int q = 0; q < 9; ++q) {
    int rr = wvid + q * 4;          // 0..35
    int kcw = rr >> 2, nt = rr & 3;
    int k0 = kcw * 32 + g * 8;
    int n = nt * 16 + m;
    bf16x8 v;
#pragma unroll
    for (int j = 0; j < 8; ++j) v[j] = f2bf(w[(k0 + j) * 64 + n]);
    *(bf16x8*)(wlds + rr * 512 + lane * 8) = v;
  }

  const float gamma = gammap[0];
  {  // cw partial sums (fp32-exact w^2), L2-hot re-read of w
    const int seg = t >> 6, o = t & 63;
    float s = 0.f;
#pragma unroll 8
    for (int k = seg * 72; k < seg * 72 + 72; ++k) {
      float v = w[k * 64 + o];
      s = fmaf(v, v, s);
    }
    red[t] = s;
  }
  __syncthreads();  // full drain: stage(0),(1), wlds, red all visible

  float cwv[4], bv[4];
#pragma unroll
  for (int nt = 0; nt < 4; ++nt) {
    int col = nt * 16 + m;
    cwv[nt] = -gamma * (red[col] + red[col + 64] + red[col + 128] + red[col + 192]);
    bv[nt] = bias[col];
  }

  // A-read byte offsets into a chunk (inverse of the staging swizzle):
  // x[k=g*8+j][l] at byte k*512 + ((l>>2 + 2g)&31)*16 + (l&3)*4
  int ab[2];
#pragma unroll
  for (int tt = 0; tt < 2; ++tt) {
    int l = wvid * 32 + tt * 16 + m;
    ab[tt] = g * 4096 + ((((l >> 2) + 2 * g) & 31) * 16) + (l & 3) * 4;
  }

  const f32x4 zero = {0.f, 0.f, 0.f, 0.f};
  f32x4 acc[2][4];
#pragma unroll
  for (int tt = 0; tt < 2; ++tt)
#pragma unroll
    for (int nt = 0; nt < 4; ++nt) acc[tt][nt] = zero;
  float x2a[2] = {0.f, 0.f};

#define COMPUTE(KC)                                                           \
  {                                                                           \
    const char* xbase = (const char*)&xs[(KC) & 1][0];                        \
    bf16x8 bfr[4];                                                            \
    _Pragma("unroll") for (int nt = 0; nt < 4; ++nt)                          \
        bfr[nt] = *(const bf16x8*)(wlds + ((KC) * 4 + nt) * 512 + lane * 8);  \
    _Pragma("unroll") for (int tt = 0; tt < 2; ++tt) {                        \
      const float* ap = (const float*)(xbase + ab[tt]);                       \
      float a[8];                                                             \
      bf16x8 afr;                                                             \
      _Pragma("unroll") for (int j = 0; j < 8; ++j) a[j] = ap[j * 128];       \
      _Pragma("unroll") for (int j = 0; j < 8; ++j) {                         \
        x2a[tt] = fmaf(a[j], a[j], x2a[tt]);                                  \
        afr[j] = f2bf(a[j]);                                                  \
      }                                                                       \
      _Pragma("unroll") for (int nt = 0; nt < 4; ++nt)                        \
          acc[tt][nt] = __builtin_amdgcn_mfma_f32_16x16x32_bf16(              \
              afr, bfr[nt], acc[tt][nt], 0, 0, 0);                            \
    }                                                                         \
  }

  // Steady state at loop top: stage(kc) done-or-draining [4/wave] +
  // stage(kc+1) in flight [4/wave] -> vmcnt(4) waits ONLY for stage(kc).
  // s_barrier (no drain!) orders buffer reuse; stage(kc+1) crosses it live.
#pragma unroll 1
  for (int kc = 0; kc < 8; ++kc) {
    asm volatile("s_waitcnt vmcnt(4)" ::: "memory");
    COMPUTE(kc)
    __builtin_amdgcn_s_barrier();
    if (kc < 7) STAGE(kc + 2, kc & 1)
  }
  asm volatile("s_waitcnt vmcnt(0)" ::: "memory");  // drain stage(8)
  COMPUTE(8)

  // ---- finish |x|^2 across the 4 k-groups
#pragma unroll
  for (int tt = 0; tt < 2; ++tt) {
    x2a[tt] += __shfl_xor(x2a[tt], 16, 64);
    x2a[tt] += __shfl_xor(x2a[tt], 32, 64);
  }

  // ---- epilogue: C/D layout col=lane&15 (=o), row=(lane>>4)*4+r (=l)
  const float coef = 2.f * gamma;
  float* ob = out + (g0 + wvid * 32) * 64;
#pragma unroll
  for (int tt = 0; tt < 2; ++tt) {
#pragma unroll
    for (int r = 0; r < 4; ++r) {
      int row = g * 4 + r;  // 0..15 within the t-tile
      float x2v = __shfl(x2a[tt], (lane & 48) | row, 64);
      float cx = -gamma * x2v;
      int lrow = tt * 16 + row;  // 0..31 within wave tile
#pragma unroll
      for (int nt = 0; nt < 4; ++nt) {
        float e = fmaf(coef, acc[tt][nt][r], cx + cwv[nt]);  // -gamma*d2
        ob[lrow * 64 + nt * 16 + m] = __expf(e) + bv[nt];
      }
    }
  }
#undef STAGE
#undef COMPUTE
}

extern "C" void kernel_launch(void* const* d_in, const int* in_sizes, int n_in,
                              void* d_out, int out_size, void* d_ws, size_t ws_size,
                              hipStream_t stream) {
  const float* x = (const float*)d_in[0];      // [8, 288, 16384]
  const float* w = (const float*)d_in[1];      // [64, 32, 3, 3] -> flat 18432
  const float* b = (const float*)d_in[2];      // [64]
  const float* gamma = (const float*)d_in[3];  // scalar
  float* out = (float*)d_out;                  // [8, 16384, 64]

  (void)d_ws; (void)ws_size;
  gauss_all<<<1024, 256, 0, stream>>>(x, w, b, gamma, out);
}